// Round 3
// baseline (2502.601 us; speedup 1.0000x reference)
//
#include <hip/hip_runtime.h>
#include <hip/hip_bf16.h>

constexpr int S   = 10;
constexpr int Bsz = 16384;
constexpr int LAG = 5;
constexpr int H   = 512;
constexpr int G4  = 4 * H;            // 2048
constexpr int F   = 5;
constexpr int BH  = Bsz * H;          // 8388608
constexpr int OUT_HN = Bsz * (S + F); // 245760
constexpr int OUT_CN = OUT_HN + 2 * BH;

typedef __attribute__((ext_vector_type(8))) short short8;   // 8 bf16 = 4 VGPRs
typedef __attribute__((ext_vector_type(4))) float f32x4;

__device__ __forceinline__ float sigf(float x) { return 1.0f / (1.0f + __expf(-x)); }
__device__ __forceinline__ float tanh_fast(float x) {
    float e = __expf(2.0f * x);
    return 1.0f - 2.0f / (e + 1.0f);
}

__device__ __forceinline__ void gload_lds16(const void* g, void* l) {
    __builtin_amdgcn_global_load_lds(
        (const __attribute__((address_space(1))) unsigned int*)g,
        (__attribute__((address_space(3))) unsigned int*)l, 16, 0, 0);
}

// ---------------------------------------------------------------------------
// Prep (gate-major):
//   W0b = bf16(Whh0) [2048,512];  W1b = bf16([Wih1 | Whh1]) [2048,1024]
//   A0r = Wih0 @ W_in [2048,5];   b0 = Wih0@b_in + bih0 + bhh0;  b1 = bih1+bhh1
// ---------------------------------------------------------------------------
__global__ __launch_bounds__(256)
void prep_kernel(const float* __restrict__ W_in,  const float* __restrict__ b_in,
                 const float* __restrict__ Wih0,  const float* __restrict__ Whh0,
                 const float* __restrict__ bih0,  const float* __restrict__ bhh0,
                 const float* __restrict__ Wih1,  const float* __restrict__ Whh1,
                 const float* __restrict__ bih1,  const float* __restrict__ bhh1,
                 __hip_bfloat16* __restrict__ W0b, __hip_bfloat16* __restrict__ W1b,
                 float* __restrict__ A0r, float* __restrict__ b0r,
                 float* __restrict__ b1r)
{
    const int r   = blockIdx.x;   // 0..2047, gate-major (PyTorch order)
    const int tid = threadIdx.x;

    for (int k = tid; k < H; k += 256)
        W0b[r * H + k] = __float2bfloat16(Whh0[r * H + k]);
    for (int k = tid; k < 2 * H; k += 256)
        W1b[r * 2 * H + k] = __float2bfloat16(
            (k < H) ? Wih1[r * H + k] : Whh1[r * H + (k - H)]);

    if (tid < LAG) {
        float s = 0.f;
        for (int h = 0; h < H; ++h) s += Wih0[r * H + h] * W_in[h * LAG + tid];
        A0r[r * LAG + tid] = s;
    } else if (tid == 5) {
        float s = 0.f;
        for (int h = 0; h < H; ++h) s += Wih0[r * H + h] * b_in[h];
        b0r[r] = s + bih0[r] + bhh0[r];
    } else if (tid == 6) {
        b1r[r] = bih1[r] + bhh1[r];
    }
}

// ---------------------------------------------------------------------------
// MFMA GEMM + fused LSTM cell (+ fused output head for layer 1).
// gates[b,r] = sum_k A[b,k]*W[r,k] + bias[r] (+ x@A0r fold for layer 0)
// Block: 128 batch rows x (32 hidden units x 4 gates). 4 waves 2x2.
// K processed in segments of 512 (seg0 = Aseg0 cols 0-511, seg1 = Aseg1
// cols 512-1023), BK=64 super-iters, per-thread hoisted pointers.
// ---------------------------------------------------------------------------
__global__ __launch_bounds__(256)
void lstm_gemm(const __hip_bfloat16* __restrict__ Aseg0,
               const __hip_bfloat16* __restrict__ Aseg1,
               int nseg,                                  // 0, 1 or 2
               const __hip_bfloat16* __restrict__ W, int ldw,
               const float* __restrict__ bias,
               const float* __restrict__ xs,   // [B,5] or null
               const float* __restrict__ A0r,  // [2048,5] or null
               const float* __restrict__ c_in, // null => c_old = 0
               float* __restrict__ c_out,
               float* __restrict__ h32_out,    // fp32 h_n slot or null
               __hip_bfloat16* __restrict__ hb16_out, // bf16 h concat buffer
               int hcol,                       // 0 (layer0) or 512 (layer1)
               const float* __restrict__ W_out, const float* __restrict__ b_out,
               const float* __restrict__ W_f,   const float* __restrict__ b_f,
               float* __restrict__ out, int s, int last)
{
    __shared__ __align__(16) short As[128 * 64];  // [row][64] 16 KB
    __shared__ __align__(16) short Bs[128 * 64];  // [cl=g*32+nn][64] 16 KB
    __shared__ float xls[128 * LAG];
    __shared__ float a0ls[128 * LAG];

    const int tid  = threadIdx.x;
    const int lane = tid & 63;
    const int quad = lane >> 4;
    const int li   = lane & 15;
    const int ww   = tid >> 6;
    const int wy   = ww >> 1;   // M dir
    const int wx   = ww & 1;    // N dir

    const int bM = blockIdx.y * 128;   // batch base
    const int cn = blockIdx.x * 32;    // hidden-unit base

    const bool has_x = (xs != nullptr);
    if (has_x) {
        for (int i = tid; i < 128 * LAG; i += 256) {
            const int row = i / LAG, l = i % LAG;
            xls[i] = xs[(size_t)(bM + row) * LAG + l];
        }
        for (int i = tid; i < 128 * LAG; i += 256) {
            const int cl = i / LAG, l = i % LAG;      // cl = g*32+nn
            const int r  = (cl >> 5) * H + cn + (cl & 31);
            a0ls[i] = A0r[r * LAG + l];
        }
    }
    __syncthreads();

    f32x4 acc[4][4];  // [m-tile][gate]
    #pragma unroll
    for (int i = 0; i < 4; ++i)
        #pragma unroll
        for (int j = 0; j < 4; ++j) acc[i][j] = (f32x4){0.f, 0.f, 0.f, 0.f};

    // per-thread staging geometry (fixed across iterations)
    size_t a_off[4], w_off[4];
    #pragma unroll
    for (int r = 0; r < 4; ++r) {
        const int idx = r * 256 + tid;
        const int row = idx >> 3;            // 0..127
        const int kc  = (idx & 7) * 8;       // 0..56
        a_off[r] = (size_t)(bM + row) * 1024 + kc;
        const int rr = (row >> 5) * H + cn + (row & 31);
        w_off[r] = (size_t)rr * ldw + kc;
    }

    for (int seg = 0; seg < nseg; ++seg) {
        const __hip_bfloat16* Abuf = seg ? Aseg1 : Aseg0;
        const __hip_bfloat16* pa[4];
        const __hip_bfloat16* pw[4];
        #pragma unroll
        for (int r = 0; r < 4; ++r) {
            pa[r] = Abuf + a_off[r] + seg * 512;
            pw[r] = W    + w_off[r] + seg * 512;
        }
        for (int t = 0; t < 8; ++t) {
            __syncthreads();
            #pragma unroll
            for (int r = 0; r < 4; ++r)
                gload_lds16(pa[r], &As[(r * 256 + tid) * 8]);
            #pragma unroll
            for (int r = 0; r < 4; ++r)
                gload_lds16(pw[r], &Bs[(r * 256 + tid) * 8]);
            #pragma unroll
            for (int r = 0; r < 4; ++r) { pa[r] += 64; pw[r] += 64; }
            __syncthreads();

            #pragma unroll
            for (int c = 0; c < 2; ++c) {
                short8 af[4], bf[4];
                #pragma unroll
                for (int mt = 0; mt < 4; ++mt)
                    af[mt] = *(const short8*)&As[(wy * 64 + mt * 16 + li) * 64 + c * 32 + quad * 8];
                #pragma unroll
                for (int g = 0; g < 4; ++g)
                    bf[g] = *(const short8*)&Bs[(g * 32 + wx * 16 + li) * 64 + c * 32 + quad * 8];
                #pragma unroll
                for (int mt = 0; mt < 4; ++mt)
                    #pragma unroll
                    for (int g = 0; g < 4; ++g)
                        acc[mt][g] = __builtin_amdgcn_mfma_f32_16x16x32_bf16(
                            af[mt], bf[g], acc[mt][g], 0, 0, 0);
            }
        }
    }

    // ---------------- epilogue: bias + x-fold + LSTM cell + head ----------
    const int n = cn + wx * 16 + li;        // this lane's hidden unit
    float bias4[4], a0reg[4][LAG];
    #pragma unroll
    for (int g = 0; g < 4; ++g) bias4[g] = bias[g * H + n];
    if (has_x) {
        #pragma unroll
        for (int g = 0; g < 4; ++g)
            #pragma unroll
            for (int l = 0; l < LAG; ++l)
                a0reg[g][l] = a0ls[(g * 32 + wx * 16 + li) * LAG + l];
    }
    const bool head = (W_out != nullptr);
    float wo = 0.f, wf[F];
    if (head) {
        wo = W_out[n];
        if (last) {
            #pragma unroll
            for (int f = 0; f < F; ++f) wf[f] = W_f[f * H + n];
        }
    }
    const bool bias_adder = (cn == 0 && wx == 0);  // one adder per row

    #pragma unroll
    for (int mt = 0; mt < 4; ++mt) {
        #pragma unroll
        for (int reg = 0; reg < 4; ++reg) {
            const int b_loc = wy * 64 + mt * 16 + quad * 4 + reg;
            const int b     = bM + b_loc;
            float g4[4];
            #pragma unroll
            for (int g = 0; g < 4; ++g) g4[g] = acc[mt][g][reg] + bias4[g];
            if (has_x) {
                #pragma unroll
                for (int l = 0; l < LAG; ++l) {
                    const float xv = xls[b_loc * LAG + l];
                    #pragma unroll
                    for (int g = 0; g < 4; ++g) g4[g] = fmaf(xv, a0reg[g][l], g4[g]);
                }
            }
            const float ig = sigf(g4[0]);
            const float fg = sigf(g4[1]);
            const float gg = tanh_fast(g4[2]);
            const float og = sigf(g4[3]);
            const float cold = c_in ? c_in[(size_t)b * H + n] : 0.f;
            const float cnew = fg * cold + ig * gg;
            const float hh   = og * tanh_fast(cnew);
            c_out[(size_t)b * H + n] = cnew;
            if (h32_out) h32_out[(size_t)b * H + n] = hh;
            hb16_out[(size_t)b * 1024 + hcol + n] = __float2bfloat16(hh);

            if (head) {
                // step_out[b,s] = sum_n h1[b,n]*W_out[n] (+ b_out once)
                float v = hh * wo;
                v += __shfl_xor(v, 1, 64);
                v += __shfl_xor(v, 2, 64);
                v += __shfl_xor(v, 4, 64);
                v += __shfl_xor(v, 8, 64);
                if (li == 0) {
                    if (bias_adder) v += b_out[0];
                    atomicAdd(&out[(size_t)b * (S + F) + s], v);
                }
                if (last) {
                    #pragma unroll
                    for (int f = 0; f < F; ++f) {
                        float vf = hh * wf[f];
                        vf += __shfl_xor(vf, 1, 64);
                        vf += __shfl_xor(vf, 2, 64);
                        vf += __shfl_xor(vf, 4, 64);
                        vf += __shfl_xor(vf, 8, 64);
                        if (li == 0) {
                            if (bias_adder) vf += b_f[f];
                            atomicAdd(&out[(size_t)b * (S + F) + S + f], vf);
                        }
                    }
                }
            }
        }
    }
}

// ---------------------------------------------------------------------------
extern "C" void kernel_launch(void* const* d_in, const int* in_sizes, int n_in,
                              void* d_out, int out_size, void* d_ws, size_t ws_size,
                              hipStream_t stream)
{
    const float* x     = (const float*)d_in[0];
    const float* W_in  = (const float*)d_in[1];
    const float* b_in  = (const float*)d_in[2];
    const float* Wih0  = (const float*)d_in[3];
    const float* Whh0  = (const float*)d_in[4];
    const float* bih0  = (const float*)d_in[5];
    const float* bhh0  = (const float*)d_in[6];
    const float* Wih1  = (const float*)d_in[7];
    const float* Whh1  = (const float*)d_in[8];
    const float* bih1  = (const float*)d_in[9];
    const float* bhh1  = (const float*)d_in[10];
    const float* W_out = (const float*)d_in[11];
    const float* b_out = (const float*)d_in[12];
    const float* W_f   = (const float*)d_in[13];
    const float* b_f   = (const float*)d_in[14];

    float* out = (float*)d_out;
    char*  ws  = (char*)d_ws;

    // workspace layout
    __hip_bfloat16* hcat0 = (__hip_bfloat16*)ws;                    // [B,1024]
    __hip_bfloat16* hcat1 = hcat0 + (size_t)Bsz * 1024;             // [B,1024]
    __hip_bfloat16* W0b   = hcat1 + (size_t)Bsz * 1024;             // [2048,512]
    __hip_bfloat16* W1b   = W0b + (size_t)G4 * H;                   // [2048,1024]
    float* A0r = (float*)(W1b + (size_t)G4 * 2 * H);                // [2048,5]
    float* b0r = A0r + G4 * LAG;
    float* b1r = b0r + G4;

    // d_out sections as state
    float* hn0 = out + OUT_HN;            // h0 fp32 (last step only)
    float* hn1 = out + OUT_HN + BH;       // h1 fp32 (last step only)
    float* c0  = out + OUT_CN;            // c0 in place
    float* c1  = out + OUT_CN + BH;       // c1 in place

    // zero step_out/fc region (head accumulates via atomics)
    hipMemsetAsync(out, 0, (size_t)OUT_HN * sizeof(float), stream);

    prep_kernel<<<dim3(G4), dim3(256), 0, stream>>>(
        W_in, b_in, Wih0, Whh0, bih0, bhh0, Wih1, Whh1, bih1, bhh1,
        W0b, W1b, A0r, b0r, b1r);

    __hip_bfloat16* hbuf[2] = {hcat0, hcat1};
    const dim3 grid(H / 32, Bsz / 128);   // (16, 128) = 2048 blocks
    const dim3 blk(256);

    for (int s = 0; s < S; ++s) {
        const bool first = (s == 0);
        const bool last  = (s == S - 1);
        __hip_bfloat16* cur  = hbuf[s & 1];
        __hip_bfloat16* prev = hbuf[(s + 1) & 1];

        // layer 0: A = h0_prev (cols 0-511 of prev), K=512
        lstm_gemm<<<grid, blk, 0, stream>>>(
            prev, nullptr, first ? 0 : 1, W0b, H, b0r,
            x + (size_t)s * Bsz * LAG, A0r,
            first ? nullptr : c0, c0, last ? hn0 : nullptr, cur, 0,
            nullptr, nullptr, nullptr, nullptr, nullptr, s, 0);

        // layer 1: A = [h0_cur cols 0-511 | h1_prev cols 512-1023], K=1024
        lstm_gemm<<<grid, blk, 0, stream>>>(
            cur, prev, first ? 1 : 2, W1b, 2 * H, b1r,
            nullptr, nullptr,
            first ? nullptr : c1, c1, last ? hn1 : nullptr, cur, H,
            W_out, b_out, W_f, b_f, out, s, last ? 1 : 0);
    }
}

// Round 4
// 1780.832 us; speedup vs baseline: 1.4053x; 1.4053x over previous
//
#include <hip/hip_runtime.h>
#include <hip/hip_bf16.h>

constexpr int S   = 10;
constexpr int Bsz = 16384;
constexpr int LAG = 5;
constexpr int H   = 512;
constexpr int G4  = 4 * H;            // 2048
constexpr int F   = 5;
constexpr int BH  = Bsz * H;          // 8388608
constexpr int OUT_HN = Bsz * (S + F); // 245760
constexpr int OUT_CN = OUT_HN + 2 * BH;

typedef __attribute__((ext_vector_type(8))) short short8;   // 8 bf16 = 4 VGPRs
typedef __attribute__((ext_vector_type(4))) float f32x4;

__device__ __forceinline__ float sigf(float x) { return 1.0f / (1.0f + __expf(-x)); }
__device__ __forceinline__ float tanh_fast(float x) {
    float e = __expf(2.0f * x);
    return 1.0f - 2.0f / (e + 1.0f);
}

__device__ __forceinline__ void gload_lds16(const void* g, void* l) {
    __builtin_amdgcn_global_load_lds(
        (const __attribute__((address_space(1))) unsigned int*)g,
        (__attribute__((address_space(3))) unsigned int*)l, 16, 0, 0);
}

// ---------------------------------------------------------------------------
// Prep (gate-major):
//   W0b = bf16(Whh0) [2048,512];  W1b = bf16([Wih1 | Whh1]) [2048,1024]
//   A0r = Wih0 @ W_in [2048,5];   b0 = Wih0@b_in + bih0 + bhh0;  b1 = bih1+bhh1
// ---------------------------------------------------------------------------
__global__ __launch_bounds__(256)
void prep_kernel(const float* __restrict__ W_in,  const float* __restrict__ b_in,
                 const float* __restrict__ Wih0,  const float* __restrict__ Whh0,
                 const float* __restrict__ bih0,  const float* __restrict__ bhh0,
                 const float* __restrict__ Wih1,  const float* __restrict__ Whh1,
                 const float* __restrict__ bih1,  const float* __restrict__ bhh1,
                 __hip_bfloat16* __restrict__ W0b, __hip_bfloat16* __restrict__ W1b,
                 float* __restrict__ A0r, float* __restrict__ b0r,
                 float* __restrict__ b1r)
{
    const int r   = blockIdx.x;   // 0..2047, gate-major (PyTorch order)
    const int tid = threadIdx.x;

    for (int k = tid; k < H; k += 256)
        W0b[r * H + k] = __float2bfloat16(Whh0[r * H + k]);
    for (int k = tid; k < 2 * H; k += 256)
        W1b[r * 2 * H + k] = __float2bfloat16(
            (k < H) ? Wih1[r * H + k] : Whh1[r * H + (k - H)]);

    if (tid < LAG) {
        float s = 0.f;
        for (int h = 0; h < H; ++h) s += Wih0[r * H + h] * W_in[h * LAG + tid];
        A0r[r * LAG + tid] = s;
    } else if (tid == 5) {
        float s = 0.f;
        for (int h = 0; h < H; ++h) s += Wih0[r * H + h] * b_in[h];
        b0r[r] = s + bih0[r] + bhh0[r];
    } else if (tid == 6) {
        b1r[r] = bih1[r] + bhh1[r];
    }
}

// ---------------------------------------------------------------------------
// MFMA GEMM + fused LSTM cell.
// gates[b,r] = sum_k A[b,k]*W[r,k] + bias[r] (+ x@A0r fold for layer 0)
// Block: 128 batch rows x (32 hidden units x 4 gates). 4 waves 2x2.
// BK=64, LDS rows of 8x16B chunks with XOR-8 swizzle: chunk (row,j) lives at
// j ^ (row&7); global source address permuted per-lane to compensate
// (global_load_lds dest stays base + lane*16).
// ---------------------------------------------------------------------------
__global__ __launch_bounds__(256)
void lstm_gemm(const __hip_bfloat16* __restrict__ Aseg0,
               const __hip_bfloat16* __restrict__ Aseg1,
               int nseg,                                  // 0, 1 or 2
               const __hip_bfloat16* __restrict__ W, int ldw,
               const float* __restrict__ bias,
               const float* __restrict__ xs,   // [B,5] or null
               const float* __restrict__ A0r,  // [2048,5] or null
               const float* __restrict__ c_in, // null => c_old = 0
               float* __restrict__ c_out,
               float* __restrict__ h32_out,    // fp32 h_n slot or null
               __hip_bfloat16* __restrict__ hb16_out, // bf16 h concat buffer
               int hcol)                       // 0 (layer0) or 512 (layer1)
{
    __shared__ __align__(16) short As[128 * 64];  // 16 KB, swizzled
    __shared__ __align__(16) short Bs[128 * 64];  // 16 KB, swizzled
    __shared__ float xls[128 * LAG];
    __shared__ float a0ls[128 * LAG];

    const int tid  = threadIdx.x;
    const int lane = tid & 63;
    const int quad = lane >> 4;
    const int li   = lane & 15;
    const int ww   = tid >> 6;
    const int wy   = ww >> 1;   // M dir
    const int wx   = ww & 1;    // N dir

    const int bM = blockIdx.y * 128;   // batch base
    const int cn = blockIdx.x * 32;    // hidden-unit base

    const bool has_x = (xs != nullptr);
    if (has_x) {
        for (int i = tid; i < 128 * LAG; i += 256) {
            const int row = i / LAG, l = i % LAG;
            xls[i] = xs[(size_t)(bM + row) * LAG + l];
        }
        for (int i = tid; i < 128 * LAG; i += 256) {
            const int cl = i / LAG, l = i % LAG;      // cl = g*32+nn
            const int r  = (cl >> 5) * H + cn + (cl & 31);
            a0ls[i] = A0r[r * LAG + l];
        }
    }
    __syncthreads();

    f32x4 acc[4][4];  // [m-tile][gate]
    #pragma unroll
    for (int i = 0; i < 4; ++i)
        #pragma unroll
        for (int j = 0; j < 4; ++j) acc[i][j] = (f32x4){0.f, 0.f, 0.f, 0.f};

    // staging geometry: thread covers 4 LDS chunks; global kc is XOR-swizzled
    size_t a_off[4], w_off[4];
    #pragma unroll
    for (int r = 0; r < 4; ++r) {
        const int idx  = r * 256 + tid;
        const int row  = idx >> 3;                      // 0..127
        const int kcg  = ((idx & 7) ^ (row & 7)) * 8;   // swizzled source col
        a_off[r] = (size_t)(bM + row) * 1024 + kcg;
        const int rr = (row >> 5) * H + cn + (row & 31);
        w_off[r] = (size_t)rr * ldw + kcg;
    }

    for (int seg = 0; seg < nseg; ++seg) {
        const __hip_bfloat16* Abuf = seg ? Aseg1 : Aseg0;
        const __hip_bfloat16* pa[4];
        const __hip_bfloat16* pw[4];
        #pragma unroll
        for (int r = 0; r < 4; ++r) {
            pa[r] = Abuf + a_off[r] + seg * 512;
            pw[r] = W    + w_off[r] + seg * 512;
        }
        for (int t = 0; t < 8; ++t) {
            __syncthreads();
            #pragma unroll
            for (int r = 0; r < 4; ++r)
                gload_lds16(pa[r], &As[(r * 256 + tid) * 8]);
            #pragma unroll
            for (int r = 0; r < 4; ++r)
                gload_lds16(pw[r], &Bs[(r * 256 + tid) * 8]);
            #pragma unroll
            for (int r = 0; r < 4; ++r) { pa[r] += 64; pw[r] += 64; }
            __syncthreads();

            #pragma unroll
            for (int c = 0; c < 2; ++c) {
                short8 af[4], bf[4];
                #pragma unroll
                for (int mt = 0; mt < 4; ++mt) {
                    const int row = wy * 64 + mt * 16 + li;
                    const int kch = (c * 4 + quad) ^ (row & 7);
                    af[mt] = *(const short8*)&As[row * 64 + kch * 8];
                }
                #pragma unroll
                for (int g = 0; g < 4; ++g) {
                    const int cl  = g * 32 + wx * 16 + li;
                    const int kch = (c * 4 + quad) ^ (cl & 7);
                    bf[g] = *(const short8*)&Bs[cl * 64 + kch * 8];
                }
                #pragma unroll
                for (int mt = 0; mt < 4; ++mt)
                    #pragma unroll
                    for (int g = 0; g < 4; ++g)
                        acc[mt][g] = __builtin_amdgcn_mfma_f32_16x16x32_bf16(
                            af[mt], bf[g], acc[mt][g], 0, 0, 0);
            }
        }
    }

    // ---------------- epilogue: bias + x-fold + LSTM cell ----------------
    const int n = cn + wx * 16 + li;        // this lane's hidden unit
    float bias4[4], a0reg[4][LAG];
    #pragma unroll
    for (int g = 0; g < 4; ++g) bias4[g] = bias[g * H + n];
    if (has_x) {
        #pragma unroll
        for (int g = 0; g < 4; ++g)
            #pragma unroll
            for (int l = 0; l < LAG; ++l)
                a0reg[g][l] = a0ls[(g * 32 + wx * 16 + li) * LAG + l];
    }

    #pragma unroll
    for (int mt = 0; mt < 4; ++mt) {
        #pragma unroll
        for (int reg = 0; reg < 4; ++reg) {
            const int b_loc = wy * 64 + mt * 16 + quad * 4 + reg;
            const int b     = bM + b_loc;
            float g4[4];
            #pragma unroll
            for (int g = 0; g < 4; ++g) g4[g] = acc[mt][g][reg] + bias4[g];
            if (has_x) {
                #pragma unroll
                for (int l = 0; l < LAG; ++l) {
                    const float xv = xls[b_loc * LAG + l];
                    #pragma unroll
                    for (int g = 0; g < 4; ++g) g4[g] = fmaf(xv, a0reg[g][l], g4[g]);
                }
            }
            const float ig = sigf(g4[0]);
            const float fg = sigf(g4[1]);
            const float gg = tanh_fast(g4[2]);
            const float og = sigf(g4[3]);
            const float cold = c_in ? c_in[(size_t)b * H + n] : 0.f;
            const float cnew = fg * cold + ig * gg;
            const float hh   = og * tanh_fast(cnew);
            c_out[(size_t)b * H + n] = cnew;
            if (h32_out) h32_out[(size_t)b * H + n] = hh;
            hb16_out[(size_t)b * 1024 + hcol + n] = __float2bfloat16(hh);
        }
    }
}

// ---------------------------------------------------------------------------
// Per-step scalar head (+ forecast head on last step). One wave per row.
// Reads bf16 h1 from hcat (cols 512..1023).
// ---------------------------------------------------------------------------
__global__ __launch_bounds__(256)
void out_head(const __hip_bfloat16* __restrict__ hcat,
              const float* __restrict__ W_out, const float* __restrict__ b_out,
              const float* __restrict__ W_f,   const float* __restrict__ b_f,
              float* __restrict__ out, int s, int last)
{
    const int wave = threadIdx.x >> 6;
    const int lane = threadIdx.x & 63;
    const int b    = blockIdx.x * 4 + wave;

    const __hip_bfloat16* hrow = hcat + (size_t)b * 1024 + 512;
    short8 hv = *(const short8*)&hrow[lane * 8];
    float h8[8];
    #pragma unroll
    for (int i = 0; i < 8; ++i) {
        union { unsigned int u; float f; } cv;
        cv.u = ((unsigned int)(unsigned short)hv[i]) << 16;
        h8[i] = cv.f;
    }

    {
        const float4 w0 = *reinterpret_cast<const float4*>(&W_out[lane * 8]);
        const float4 w1 = *reinterpret_cast<const float4*>(&W_out[lane * 8 + 4]);
        const float w8[8] = {w0.x, w0.y, w0.z, w0.w, w1.x, w1.y, w1.z, w1.w};
        float v = 0.f;
        #pragma unroll
        for (int i = 0; i < 8; ++i) v = fmaf(h8[i], w8[i], v);
        #pragma unroll
        for (int off = 32; off > 0; off >>= 1) v += __shfl_down(v, off, 64);
        if (lane == 0) out[b * (S + F) + s] = v + b_out[0];
    }
    if (last) {
        for (int f = 0; f < F; ++f) {
            const float4 w0 = *reinterpret_cast<const float4*>(&W_f[f * H + lane * 8]);
            const float4 w1 = *reinterpret_cast<const float4*>(&W_f[f * H + lane * 8 + 4]);
            const float w8[8] = {w0.x, w0.y, w0.z, w0.w, w1.x, w1.y, w1.z, w1.w};
            float v = 0.f;
            #pragma unroll
            for (int i = 0; i < 8; ++i) v = fmaf(h8[i], w8[i], v);
            #pragma unroll
            for (int off = 32; off > 0; off >>= 1) v += __shfl_down(v, off, 64);
            if (lane == 0) out[b * (S + F) + S + f] = v + b_f[f];
        }
    }
}

// ---------------------------------------------------------------------------
extern "C" void kernel_launch(void* const* d_in, const int* in_sizes, int n_in,
                              void* d_out, int out_size, void* d_ws, size_t ws_size,
                              hipStream_t stream)
{
    const float* x     = (const float*)d_in[0];
    const float* W_in  = (const float*)d_in[1];
    const float* b_in  = (const float*)d_in[2];
    const float* Wih0  = (const float*)d_in[3];
    const float* Whh0  = (const float*)d_in[4];
    const float* bih0  = (const float*)d_in[5];
    const float* bhh0  = (const float*)d_in[6];
    const float* Wih1  = (const float*)d_in[7];
    const float* Whh1  = (const float*)d_in[8];
    const float* bih1  = (const float*)d_in[9];
    const float* bhh1  = (const float*)d_in[10];
    const float* W_out = (const float*)d_in[11];
    const float* b_out = (const float*)d_in[12];
    const float* W_f   = (const float*)d_in[13];
    const float* b_f   = (const float*)d_in[14];

    float* out = (float*)d_out;
    char*  ws  = (char*)d_ws;

    // workspace layout
    __hip_bfloat16* hcat0 = (__hip_bfloat16*)ws;                    // [B,1024]
    __hip_bfloat16* hcat1 = hcat0 + (size_t)Bsz * 1024;             // [B,1024]
    __hip_bfloat16* W0b   = hcat1 + (size_t)Bsz * 1024;             // [2048,512]
    __hip_bfloat16* W1b   = W0b + (size_t)G4 * H;                   // [2048,1024]
    float* A0r = (float*)(W1b + (size_t)G4 * 2 * H);                // [2048,5]
    float* b0r = A0r + G4 * LAG;
    float* b1r = b0r + G4;

    // d_out sections as state
    float* hn0 = out + OUT_HN;            // h0 fp32 (last step only)
    float* hn1 = out + OUT_HN + BH;       // h1 fp32 (last step only)
    float* c0  = out + OUT_CN;            // c0 in place
    float* c1  = out + OUT_CN + BH;       // c1 in place

    prep_kernel<<<dim3(G4), dim3(256), 0, stream>>>(
        W_in, b_in, Wih0, Whh0, bih0, bhh0, Wih1, Whh1, bih1, bhh1,
        W0b, W1b, A0r, b0r, b1r);

    __hip_bfloat16* hbuf[2] = {hcat0, hcat1};
    const dim3 grid(H / 32, Bsz / 128);   // (16, 128) = 2048 blocks
    const dim3 blk(256);

    for (int s = 0; s < S; ++s) {
        const bool first = (s == 0);
        const bool last  = (s == S - 1);
        __hip_bfloat16* cur  = hbuf[s & 1];
        __hip_bfloat16* prev = hbuf[(s + 1) & 1];

        // layer 0: A = h0_prev (cols 0-511 of prev), K=512
        lstm_gemm<<<grid, blk, 0, stream>>>(
            prev, nullptr, first ? 0 : 1, W0b, H, b0r,
            x + (size_t)s * Bsz * LAG, A0r,
            first ? nullptr : c0, c0, last ? hn0 : nullptr, cur, 0);

        // layer 1: A = [h0_cur cols 0-511 | h1_prev cols 512-1023], K=1024
        lstm_gemm<<<grid, blk, 0, stream>>>(
            cur, prev, first ? 1 : 2, W1b, 2 * H, b1r,
            nullptr, nullptr,
            first ? nullptr : c1, c1, last ? hn1 : nullptr, cur, H);

        out_head<<<dim3(Bsz / 4), blk, 0, stream>>>(
            cur, W_out, b_out, W_f, b_f, out, s, last ? 1 : 0);
    }
}